// Round 1
// baseline (9854.454 us; speedup 1.0000x reference)
//
#include <hip/hip_runtime.h>
#include <hip/hip_bf16.h>

using short8v = __attribute__((ext_vector_type(8))) short;
using float4v = __attribute__((ext_vector_type(4))) float;
typedef unsigned int uint32;

#define MFMA_B16(a,b,c) __builtin_amdgcn_mfma_f32_16x16x32_bf16((a),(b),(c),0,0,0)

constexpr int Bc = 256, Tc = 256, Dc = 128, Hc = 1024;
constexpr int KB_L = 19;   // kb (K/32) units of weights resident in LDS per tile
constexpr int KB_V = 21;   // kb units resident in VGPRs per tile (total 40 = K1280/32)

// ---- workspace layout (bytes) ----
constexpr size_t OFF_FA   = 0;                       // flags A: 8 groups * 32 int
constexpr size_t OFF_FB   = 1024;                    // flags B
constexpr size_t OFF_HDEC = 4096;                    // 8*32*1024 bf16 = 524288
constexpr size_t OFF_RH   = OFF_HDEC + 524288;       // 524288
constexpr size_t OFF_HT   = OFF_RH + 524288;         // 256*1024 f32 = 1048576
constexpr size_t OFF_XM   = 4u << 20;                // [T][B][256] bf16 = 33554432
constexpr size_t OFF_WL   = OFF_XM + 33554432;       // 32*6*19*512*2 = 3735552
constexpr size_t OFF_WV   = OFF_WL + 3735552;        // 32*6*21*512*2 = 4128768
constexpr size_t OFF_WG   = OFF_WV + 4128768;        // 32*2*4*512*2  = 262144
constexpr size_t OFF_BIAS = OFF_WG + 262144;         // 32*96 f32 = 12288
constexpr size_t OFF_BG   = OFF_BIAS + 12288;        // 32*32 f32 = 4096

// ---- LDS layout (bytes) ----
constexpr int LO_WL   = 0;        // 6*19*512*2 = 116736
constexpr int LO_ACH  = 116736;   // 32*264*2   = 16896  (A-chunk, pad 8 -> b128 conflict floor)
constexpr int LO_MBUF = 133632;   // 32*136*2   = 8704   (m(t+1))
constexpr int LO_ZBUF = 142336;   // 32*33*4    = 4224
constexpr int LO_GBUF = 146560;   // 4224
constexpr int LO_WGAM = 150784;   // 2*4*512*2  = 8192
constexpr int LO_BIAS = 158976;   // 96*4
constexpr int LO_BG   = 159360;   // 32*4  -> total 159488
constexpr int SMEM_BYTES = 159488;

__device__ __forceinline__ unsigned short f2bf(float f) {
  __hip_bfloat16 h = __float2bfloat16(f);
  return *reinterpret_cast<unsigned short*>(&h);
}
__device__ __forceinline__ float bf2f(unsigned short s) {
  return __uint_as_float(((unsigned int)s) << 16);
}
__device__ __forceinline__ uint32 ld_coh(const uint32* p) {
  return __hip_atomic_load(p, __ATOMIC_RELAXED, __HIP_MEMORY_SCOPE_AGENT);
}

// zero flags + h_dec (re-run every launch: ws is poisoned each call)
__global__ void k_init(char* __restrict__ ws) {
  int id = blockIdx.x * 256 + threadIdx.x;
  if (id < 132096) ((uint32*)ws)[id] = 0u;   // covers [0, 528384) = flags + h_dec
}

// build xm[t][b][0:128]=bf16(x'), [128:256]=bf16(m)
__global__ void k_xm(const float* __restrict__ x, const float* __restrict__ delta,
                     const float* __restrict__ m, const float* __restrict__ wgx,
                     const float* __restrict__ bgx, unsigned short* __restrict__ xm) {
  const int eid = blockIdx.x * 256 + threadIdx.x;      // 8388608 total
  const int d = eid & 127; const int bt = eid >> 7;
  const int t = bt >> 8;   const int b = bt & 255;
  const size_t ii = ((size_t)b * Tc + t) * Dc + d;
  const float xv = x[ii], dv = delta[ii], mv = m[ii];
  const float dx = dv * wgx[d] + bgx[d];
  const float xo = (mv > 0.f) ? (1.f - dx) * 0.001f : xv;   // where(m>0, x_replace, x)
  const size_t o = ((size_t)t * Bc + b) * 256;
  xm[o + d] = f2bf(xo);
  xm[o + 128 + d] = f2bf(mv);
}

// pack weights into MFMA-fragment-ready layout + fold mi@V into bias
__global__ void k_pack(const float* __restrict__ Wz, const float* __restrict__ Uz,
                       const float* __restrict__ Vz, const float* __restrict__ bz,
                       const float* __restrict__ Wr, const float* __restrict__ Ur,
                       const float* __restrict__ Vr, const float* __restrict__ br,
                       const float* __restrict__ Wh, const float* __restrict__ Uh,
                       const float* __restrict__ Vh, const float* __restrict__ bh,
                       const float* __restrict__ Wgh, const float* __restrict__ bgh,
                       char* __restrict__ ws) {
  unsigned short* wL = (unsigned short*)(ws + OFF_WL);
  unsigned short* wV = (unsigned short*)(ws + OFF_WV);
  unsigned short* wG = (unsigned short*)(ws + OFF_WG);
  float* bias = (float*)(ws + OFF_BIAS);
  float* bg   = (float*)(ws + OFF_BG);
  const int id = blockIdx.x * 256 + threadIdx.x;       // 512000 total exactly
  if (id < 491520) {
    const int l = id & 63; int u = id >> 6;
    const int kb = u % 40; u /= 40;
    const int tile = u % 6; const int mem = u / 6;
    const int role = tile >> 1;                         // 0=z,1=r,2=h~
    const float* Wm = role == 0 ? Wz : (role == 1 ? Wr : Wh);
    const float* Vm = role == 0 ? Vz : (role == 1 ? Vr : Vh);
    const float* Um = role == 0 ? Uz : (role == 1 ? Ur : Uh);
    const int col = mem * 32 + (tile & 1) * 16 + (l & 15);
    const int k0 = kb * 32 + (l >> 4) * 8;
    unsigned short* dst = (kb < KB_L)
      ? wL + ((((size_t)mem * 6 + tile) * KB_L + kb) * 64 + l) * 8
      : wV + ((((size_t)mem * 6 + tile) * KB_V + (kb - KB_L)) * 64 + l) * 8;
    #pragma unroll
    for (int e = 0; e < 8; ++e) {
      const int k = k0 + e; float v;
      if (k < 128)      v =  Wm[(size_t)k * Hc + col];
      else if (k < 256) v = -Vm[(size_t)(k - 128) * Hc + col];
      else              v =  Um[(size_t)(k - 256) * Hc + col];
      dst[e] = f2bf(v);
    }
  } else if (id < 507904) {                             // gamma weights
    const int id2 = id - 491520;
    const int l = id2 & 63; int u = id2 >> 6;
    const int kb = u & 3; u >>= 2;
    const int tile = u & 1; const int mem = u >> 1;
    const int col = mem * 32 + tile * 16 + (l & 15);
    const int k0 = kb * 32 + (l >> 4) * 8;
    unsigned short* dst = wG + ((((size_t)mem * 2 + tile) * 4 + kb) * 64 + l) * 8;
    #pragma unroll
    for (int e = 0; e < 8; ++e) dst[e] = f2bf(Wgh[(size_t)(k0 + e) * Hc + col]);
  } else if (id < 510976) {                             // bias = b + colsum(V)
    const int id3 = id - 507904;
    const int c16 = id3 & 15; int u = id3 >> 4;
    const int tile = u % 6; const int mem = u / 6;
    const int role = tile >> 1;
    const float* Vm = role == 0 ? Vz : (role == 1 ? Vr : Vh);
    const float* bm = role == 0 ? bz : (role == 1 ? br : bh);
    const int col = mem * 32 + (tile & 1) * 16 + c16;
    float s = bm[col];
    for (int d = 0; d < 128; ++d) s += Vm[(size_t)d * Hc + col];
    bias[mem * 96 + tile * 16 + c16] = s;
  } else if (id < 512000) {
    const int id4 = id - 510976;
    bg[id4] = bgh[id4];
  }
}

// stage a [32 rows][256 K] bf16 chunk of a broadcast buffer into LDS (coherent loads)
__device__ __forceinline__ void stage_bcast(const unsigned short* gsrc, int colbase,
                                            short* dst, int tid) {
  const int r = tid >> 4, c = tid & 15;
  const uint32* src = (const uint32*)(gsrc + (size_t)r * Hc + colbase) + c * 8;
  uint32 a0 = ld_coh(src + 0), a1 = ld_coh(src + 1), a2 = ld_coh(src + 2), a3 = ld_coh(src + 3);
  uint32 a4 = ld_coh(src + 4), a5 = ld_coh(src + 5), a6 = ld_coh(src + 6), a7 = ld_coh(src + 7);
  uint32* d = (uint32*)(dst + r * 264 + c * 16);
  d[0] = a0; d[1] = a1; d[2] = a2; d[3] = a3; d[4] = a4; d[5] = a5; d[6] = a6; d[7] = a7;
}

template<int S>
__device__ __forceinline__ void mfma_slot(const short* ach, const short* wlr,
                                          const short8v (&vw)[2][KB_V], int arow, int l,
                                          float4v& a0, float4v& a1) {
  #pragma unroll
  for (int kk = 0; kk < 8; ++kk) {
    const int kb = S * 8 + kk;
    short8v av = *(const short8v*)(ach + arow + kk * 32);
    short8v b0, b1;
    if (kb < KB_L) {
      b0 = *(const short8v*)(wlr + ((0 * KB_L + kb) * 64 + l) * 8);
      b1 = *(const short8v*)(wlr + ((1 * KB_L + kb) * 64 + l) * 8);
    } else {
      b0 = vw[0][kb - KB_L]; b1 = vw[1][kb - KB_L];
    }
    a0 = MFMA_B16(av, b0, a0);
    a1 = MFMA_B16(av, b1, a1);
  }
}

__global__ __launch_bounds__(512, 2) void k_grud(const unsigned short* __restrict__ xm,
                                                 char* __restrict__ ws) {
  extern __shared__ char smem[];
  short* wL   = (short*)(smem + LO_WL);
  short* ach  = (short*)(smem + LO_ACH);
  short* mbuf = (short*)(smem + LO_MBUF);
  float* zbuf = (float*)(smem + LO_ZBUF);
  float* gbuf = (float*)(smem + LO_GBUF);
  short* wgam = (short*)(smem + LO_WGAM);
  float* bias = (float*)(smem + LO_BIAS);
  float* bg   = (float*)(smem + LO_BG);

  const int bid = blockIdx.x, g = bid & 7, mem = bid >> 3;
  const int tid = threadIdx.x, w = tid >> 6, l = tid & 63;
  const int l15 = l & 15, q4 = l >> 4;
  const int role = w >> 1, mt = w & 1;   // waves: 0,1=z(mt0/1) 2,3=r 4,5=h~ 6,7=gamma

  int* fA = (int*)(ws + OFF_FA) + g * 32;
  int* fB = (int*)(ws + OFF_FB) + g * 32;
  unsigned short* hdec = (unsigned short*)(ws + OFF_HDEC) + (size_t)g * 32 * Hc;
  unsigned short* rhb  = (unsigned short*)(ws + OFF_RH)  + (size_t)g * 32 * Hc;
  float* hT = (float*)(ws + OFF_HT);
  const short* wLg = (const short*)(ws + OFF_WL) + (size_t)mem * (6 * KB_L * 512);
  const short* wVg = (const short*)(ws + OFF_WV) + (size_t)mem * (6 * KB_V * 512);
  const short* wGg = (const short*)(ws + OFF_WG) + (size_t)mem * (2 * 4 * 512);
  const float* biasg = (const float*)(ws + OFF_BIAS) + mem * 96;
  const float* bgg   = (const float*)(ws + OFF_BG) + mem * 32;

  for (int i = tid; i < 6 * KB_L * 512 / 8; i += 512) ((uint4*)wL)[i] = ((const uint4*)wLg)[i];
  for (int i = tid; i < 512; i += 512) ((uint4*)wgam)[i] = ((const uint4*)wGg)[i];
  if (tid < 96) bias[tid] = biasg[tid];
  if (tid < 32) bg[tid] = bgg[tid];

  short8v vw[2][KB_V];
  if (w < 6) {
    #pragma unroll
    for (int c = 0; c < 2; ++c)
      #pragma unroll
      for (int i = 0; i < KB_V; ++i)
        vw[c][i] = *(const short8v*)(wVg + (size_t)(((role * 2 + c) * KB_V + i) * 64 + l) * 8);
  }
  const short* wlr = wL + role * (2 * KB_L * 512);
  const int arow = (mt * 16 + l15) * 264 + q4 * 8;
  __syncthreads();

  float4v acc0, acc1;
  #pragma unroll 1
  for (int t = 0; t < 256; ++t) {
    const unsigned short* xmt = xm + (size_t)(t * Bc + g * 32) * 256;
    {   // stage slot0: xm(t) -> ach ; m(t+1) -> mbuf
      const int r = tid >> 4, c = tid & 15;
      const uint4* s0 = (const uint4*)(xmt + (size_t)r * 256) + c * 2;
      uint4 v0 = s0[0], v1 = s0[1];
      *(uint4*)(ach + r * 264 + c * 16) = v0;
      *(uint4*)(ach + r * 264 + c * 16 + 8) = v1;
      if (t < 255) {
        uint4 mv = *(const uint4*)(xmt + (size_t)Bc * 256 + (size_t)r * 256 + 128 + c * 8);
        *(uint4*)(mbuf + r * 136 + c * 8) = mv;
      }
    }
    __syncthreads();
    if (w < 6) {
      acc0 = float4v{0.f, 0.f, 0.f, 0.f};
      acc1 = float4v{0.f, 0.f, 0.f, 0.f};
      mfma_slot<0>(ach, wlr, vw, arow, l, acc0, acc1);
    } else if (t < 255) {   // gamma(t+1) for member's h~ cols
      float4v ga0{0.f, 0.f, 0.f, 0.f}, ga1{0.f, 0.f, 0.f, 0.f};
      const int marow = (mt * 16 + l15) * 136 + q4 * 8;
      #pragma unroll
      for (int kb = 0; kb < 4; ++kb) {
        short8v av = *(const short8v*)(mbuf + marow + kb * 32);
        short8v b0 = *(const short8v*)(wgam + ((0 * 4 + kb) * 64 + l) * 8);
        short8v b1 = *(const short8v*)(wgam + ((1 * 4 + kb) * 64 + l) * 8);
        ga0 = MFMA_B16(av, b0, ga0);
        ga1 = MFMA_B16(av, b1, ga1);
      }
      #pragma unroll
      for (int q = 0; q < 4; ++q) {
        const int row = mt * 16 + q4 * 4 + q;
        gbuf[l15 * 33 + row]        = __expf(-fmaxf(0.f, ga0[q] + bg[l15]));
        gbuf[(16 + l15) * 33 + row] = __expf(-fmaxf(0.f, ga1[q] + bg[16 + l15]));
      }
    }
    if (w == 0) {   // wait all members finished phase B(t-1)
      int sp = 0;
      while (true) {
        int v = (l < 32) ? __hip_atomic_load(&fB[l], __ATOMIC_RELAXED, __HIP_MEMORY_SCOPE_AGENT)
                         : 0x7fffffff;
        if (__all(v >= t)) break;
        if (++sp > 32768) break;
        __builtin_amdgcn_s_sleep(2);
      }
    }
    __syncthreads();
    // ---- phase A: K = h_dec, four chunks
    stage_bcast(hdec, 0, ach, tid);   __syncthreads();
    if (w < 4) mfma_slot<1>(ach, wlr, vw, arow, l, acc0, acc1);  __syncthreads();
    stage_bcast(hdec, 256, ach, tid); __syncthreads();
    if (w < 4) mfma_slot<2>(ach, wlr, vw, arow, l, acc0, acc1);  __syncthreads();
    stage_bcast(hdec, 512, ach, tid); __syncthreads();
    if (w < 4) mfma_slot<3>(ach, wlr, vw, arow, l, acc0, acc1);  __syncthreads();
    stage_bcast(hdec, 768, ach, tid); __syncthreads();
    if (w < 4) mfma_slot<4>(ach, wlr, vw, arow, l, acc0, acc1);  __syncthreads();
    if (w < 2) {          // z = sigmoid -> zbuf (kept for update)
      #pragma unroll
      for (int c = 0; c < 2; ++c) {
        float4v a = c ? acc1 : acc0;
        #pragma unroll
        for (int q = 0; q < 4; ++q) {
          const int row = mt * 16 + q4 * 4 + q;
          zbuf[(c * 16 + l15) * 33 + row] = 1.f / (1.f + __expf(-(a[q] + bias[c * 16 + l15])));
        }
      }
    } else if (w < 4) {   // r -> rh = r * h_dec -> global broadcast
      #pragma unroll
      for (int c = 0; c < 2; ++c) {
        float4v a = c ? acc1 : acc0;
        #pragma unroll
        for (int q = 0; q < 4; ++q) {
          const int row = mt * 16 + q4 * 4 + q;
          const int col = mem * 32 + c * 16 + l15;
          const float rv = 1.f / (1.f + __expf(-(a[q] + bias[32 + c * 16 + l15])));
          const size_t eix = (size_t)row * Hc + col;
          const uint32 vv = ld_coh((const uint32*)hdec + (eix >> 1));
          const float hd = bf2f((l15 & 1) ? (unsigned short)(vv >> 16) : (unsigned short)(vv & 0xffffu));
          rhb[eix] = f2bf(rv * hd);
        }
      }
    }
    __syncthreads();
    if (tid == 0) {
      __threadfence();   // push rh to coherence point before flag
      __hip_atomic_store(&fA[mem], t + 1, __ATOMIC_RELAXED, __HIP_MEMORY_SCOPE_AGENT);
    }
    if (w == 0) {
      int sp = 0;
      while (true) {
        int v = (l < 32) ? __hip_atomic_load(&fA[l], __ATOMIC_RELAXED, __HIP_MEMORY_SCOPE_AGENT)
                         : 0x7fffffff;
        if (__all(v >= t + 1)) break;
        if (++sp > 32768) break;
        __builtin_amdgcn_s_sleep(2);
      }
    }
    __syncthreads();
    // ---- phase B: K = rh, four chunks (h~ waves)
    stage_bcast(rhb, 0, ach, tid);   __syncthreads();
    if (w == 4 || w == 5) mfma_slot<1>(ach, wlr, vw, arow, l, acc0, acc1); __syncthreads();
    stage_bcast(rhb, 256, ach, tid); __syncthreads();
    if (w == 4 || w == 5) mfma_slot<2>(ach, wlr, vw, arow, l, acc0, acc1); __syncthreads();
    stage_bcast(rhb, 512, ach, tid); __syncthreads();
    if (w == 4 || w == 5) mfma_slot<3>(ach, wlr, vw, arow, l, acc0, acc1); __syncthreads();
    stage_bcast(rhb, 768, ach, tid); __syncthreads();
    if (w == 4 || w == 5) mfma_slot<4>(ach, wlr, vw, arow, l, acc0, acc1); __syncthreads();
    if (w == 4 || w == 5) {   // h~ , h_new, h_dec(t+1) = gamma(t+1)*h_new
      #pragma unroll
      for (int c = 0; c < 2; ++c) {
        float4v a = c ? acc1 : acc0;
        #pragma unroll
        for (int q = 0; q < 4; ++q) {
          const int row = mt * 16 + q4 * 4 + q;
          const int col = mem * 32 + c * 16 + l15;
          const float e = __expf(2.f * (a[q] + bias[64 + c * 16 + l15]));
          const float ht = 1.f - 2.f / (e + 1.f);   // tanh, overflow-safe
          const float zv = zbuf[(c * 16 + l15) * 33 + row];
          const size_t eix = (size_t)row * Hc + col;
          const uint32 vv = ld_coh((const uint32*)hdec + (eix >> 1));
          const float hd = bf2f((l15 & 1) ? (unsigned short)(vv >> 16) : (unsigned short)(vv & 0xffffu));
          const float hn = (1.f - zv) * hd + zv * ht;
          if (t < 255) {
            hdec[eix] = f2bf(gbuf[(c * 16 + l15) * 33 + row] * hn);
          } else {
            hT[(size_t)(g * 32 + row) * Hc + col] = hn;
          }
        }
      }
    }
    __syncthreads();
    if (tid == 0) {
      __threadfence();
      __hip_atomic_store(&fB[mem], t + 1, __ATOMIC_RELAXED, __HIP_MEMORY_SCOPE_AGENT);
    }
  }
}

// out = h_T @ dec_W + dec_b
__global__ void k_dec(const char* __restrict__ ws, const float* __restrict__ decW,
                      const float* __restrict__ decb, float* __restrict__ out) {
  const float* hT = (const float*)(ws + OFF_HT);
  __shared__ float red[4][64];
  const int b = blockIdx.x, tid = threadIdx.x;
  const int col = tid & 63, part = tid >> 6;
  float acc = 0.f;
  const float* hrow = hT + (size_t)b * Hc + part * 256;
  for (int i = 0; i < 256; ++i) acc += hrow[i] * decW[(size_t)(part * 256 + i) * 64 + col];
  red[part][col] = acc;
  __syncthreads();
  if (part == 0) out[b * 64 + col] = red[0][col] + red[1][col] + red[2][col] + red[3][col] + decb[col];
}

extern "C" void kernel_launch(void* const* d_in, const int* in_sizes, int n_in,
                              void* d_out, int out_size, void* d_ws, size_t ws_size,
                              hipStream_t stream) {
  const float* x    = (const float*)d_in[0];
  const float* delt = (const float*)d_in[1];
  const float* m    = (const float*)d_in[2];
  const float* W_r = (const float*)d_in[3],  *U_r = (const float*)d_in[4];
  const float* V_r = (const float*)d_in[5],  *b_r = (const float*)d_in[6];
  const float* W_z = (const float*)d_in[7],  *U_z = (const float*)d_in[8];
  const float* V_z = (const float*)d_in[9],  *b_z = (const float*)d_in[10];
  const float* W_h = (const float*)d_in[11], *U_h = (const float*)d_in[12];
  const float* V_h = (const float*)d_in[13], *b_h = (const float*)d_in[14];
  const float* Wgx = (const float*)d_in[15], *bgx = (const float*)d_in[16];
  const float* Wgh = (const float*)d_in[17], *bgh = (const float*)d_in[18];
  const float* dW  = (const float*)d_in[19], *db  = (const float*)d_in[20];
  char* ws = (char*)d_ws;
  float* out = (float*)d_out;

  (void)hipFuncSetAttribute((const void*)k_grud,
                            hipFuncAttributeMaxDynamicSharedMemorySize, SMEM_BYTES);

  k_init<<<516, 256, 0, stream>>>(ws);
  k_xm<<<32768, 256, 0, stream>>>(x, delt, m, Wgx, bgx, (unsigned short*)(ws + OFF_XM));
  k_pack<<<2000, 256, 0, stream>>>(W_z, U_z, V_z, b_z, W_r, U_r, V_r, b_r,
                                   W_h, U_h, V_h, b_h, Wgh, bgh, ws);
  k_grud<<<256, 512, SMEM_BYTES, stream>>>((const unsigned short*)(ws + OFF_XM), ws);
  k_dec<<<256, 256, 0, stream>>>(ws, dW, db, out);
}

// Round 2
// 3900.016 us; speedup vs baseline: 2.5268x; 2.5268x over previous
//
#include <hip/hip_runtime.h>
#include <hip/hip_bf16.h>

using short8v = __attribute__((ext_vector_type(8))) short;
using float4v = __attribute__((ext_vector_type(4))) float;
typedef unsigned int uint32;

#define MFMA_B16(a,b,c) __builtin_amdgcn_mfma_f32_16x16x32_bf16((a),(b),(c),0,0,0)

constexpr int Bc = 256, Tc = 256, Dc = 128, Hc = 1024;
constexpr int KB_L = 19;   // kb (K/32) units resident in LDS
constexpr int KB_V = 12;   // kb units resident in VGPRs
constexpr int KB_S = 9;    // kb units streamed from global (L2-cached)

// ---- workspace layout (bytes) ----
constexpr size_t OFF_FA   = 0;                       // flags A: 8 groups * 32 int
constexpr size_t OFF_FB   = 1024;                    // flags B
constexpr size_t OFF_HDEC = 4096;                    // 8*32*1024 bf16 = 524288
constexpr size_t OFF_RH   = OFF_HDEC + 524288;       // 524288
constexpr size_t OFF_HT   = OFF_RH + 524288;         // 256*1024 f32 = 1048576
constexpr size_t OFF_XM   = 4u << 20;                // [T][B][256] bf16 = 33554432
constexpr size_t OFF_WL   = OFF_XM + 33554432;       // 32*6*19*512*2 = 3735552
constexpr size_t OFF_WV   = OFF_WL + 3735552;        // 32*6*12*512*2 = 2359296
constexpr size_t OFF_WS   = OFF_WV + 2359296;        // 32*6*9*512*2  = 1769472
constexpr size_t OFF_WG   = OFF_WS + 1769472;        // 32*2*4*512*2  = 262144
constexpr size_t OFF_BIAS = OFF_WG + 262144;         // 32*96 f32 = 12288
constexpr size_t OFF_BG   = OFF_BIAS + 12288;        // 32*32 f32 = 4096

// ---- LDS layout (bytes) ----
constexpr int LO_WL   = 0;        // 6*19*1024 = 116736
constexpr int LO_ACH0 = 116736;   // 16384  (chunk buf 0, swizzled, no pad)
constexpr int LO_ACH1 = 133120;   // 16384  (chunk buf 1)
constexpr int LO_ZBUF = 149504;   // 32*33*4 = 4224
constexpr int LO_GBUF = 153728;   // 4224
constexpr int LO_HBUF = 157952;   // 32*33*2 = 2112 (own-col h_dec bf16)
constexpr int LO_BIAS = 160064;   // 96*4
constexpr int LO_BG   = 160448;   // 32*4 -> total 160576
constexpr int SMEM_BYTES = 160576;

typedef __attribute__((address_space(1))) const unsigned int g_as1_u32;
typedef __attribute__((address_space(3))) unsigned int l_as3_u32;

__device__ __forceinline__ unsigned short f2bf(float f) {
  __hip_bfloat16 h = __float2bfloat16(f);
  return *reinterpret_cast<unsigned short*>(&h);
}
__device__ __forceinline__ float bf2f(unsigned short s) {
  return __uint_as_float(((unsigned int)s) << 16);
}

#define BARX() asm volatile("s_waitcnt lgkmcnt(0)\n\ts_barrier" ::: "memory")
#define WAITV2() asm volatile("s_waitcnt vmcnt(2)" ::: "memory")
#define WAITV0() asm volatile("s_waitcnt vmcnt(0)" ::: "memory")

// zero flags + h_dec, straight to LLC (no dirty L2 lines anywhere)
__global__ void k_init(char* __restrict__ ws) {
  int id = blockIdx.x * 256 + threadIdx.x;
  if (id < 132096) {
    uint32* p = (uint32*)ws + id;
    __hip_atomic_store(p, 0u, __ATOMIC_RELAXED, __HIP_MEMORY_SCOPE_AGENT);
  }
}

// build xm[t][b][0:128]=bf16(x'), [128:256]=bf16(m)
__global__ void k_xm(const float* __restrict__ x, const float* __restrict__ delta,
                     const float* __restrict__ m, const float* __restrict__ wgx,
                     const float* __restrict__ bgx, unsigned short* __restrict__ xm) {
  const int eid = blockIdx.x * 256 + threadIdx.x;      // 8388608 total
  const int d = eid & 127; const int bt = eid >> 7;
  const int t = bt >> 8;   const int b = bt & 255;
  const size_t ii = ((size_t)b * Tc + t) * Dc + d;
  const float xv = x[ii], dv = delta[ii], mv = m[ii];
  const float dx = dv * wgx[d] + bgx[d];
  const float xo = (mv > 0.f) ? (1.f - dx) * 0.001f : xv;
  const size_t o = ((size_t)t * Bc + b) * 256;
  xm[o + d] = f2bf(xo);
  xm[o + 128 + d] = f2bf(mv);
}

// pack weights into MFMA-fragment-ready layout + fold mi@V into bias
__global__ void k_pack(const float* __restrict__ Wz, const float* __restrict__ Uz,
                       const float* __restrict__ Vz, const float* __restrict__ bz,
                       const float* __restrict__ Wr, const float* __restrict__ Ur,
                       const float* __restrict__ Vr, const float* __restrict__ br,
                       const float* __restrict__ Wh, const float* __restrict__ Uh,
                       const float* __restrict__ Vh, const float* __restrict__ bh,
                       const float* __restrict__ Wgh, const float* __restrict__ bgh,
                       char* __restrict__ ws) {
  unsigned short* wL = (unsigned short*)(ws + OFF_WL);
  unsigned short* wV = (unsigned short*)(ws + OFF_WV);
  unsigned short* wS = (unsigned short*)(ws + OFF_WS);
  unsigned short* wG = (unsigned short*)(ws + OFF_WG);
  float* bias = (float*)(ws + OFF_BIAS);
  float* bg   = (float*)(ws + OFF_BG);
  const int id = blockIdx.x * 256 + threadIdx.x;       // 512000 total exactly
  if (id < 491520) {
    const int l = id & 63; int u = id >> 6;
    const int kb = u % 40; u /= 40;
    const int tile = u % 6; const int mem = u / 6;
    const int role = tile >> 1;                         // 0=z,1=r,2=h~
    const float* Wm = role == 0 ? Wz : (role == 1 ? Wr : Wh);
    const float* Vm = role == 0 ? Vz : (role == 1 ? Vr : Vh);
    const float* Um = role == 0 ? Uz : (role == 1 ? Ur : Uh);
    const int col = mem * 32 + (tile & 1) * 16 + (l & 15);
    const int k0 = kb * 32 + (l >> 4) * 8;
    unsigned short* dst;
    if (kb < KB_L)
      dst = wL + ((((size_t)mem * 6 + tile) * KB_L + kb) * 64 + l) * 8;
    else if (kb < KB_L + KB_V)
      dst = wV + ((((size_t)mem * 6 + tile) * KB_V + (kb - KB_L)) * 64 + l) * 8;
    else
      dst = wS + ((((size_t)mem * 6 + tile) * KB_S + (kb - KB_L - KB_V)) * 64 + l) * 8;
    #pragma unroll
    for (int e = 0; e < 8; ++e) {
      const int k = k0 + e; float v;
      if (k < 128)      v =  Wm[(size_t)k * Hc + col];
      else if (k < 256) v = -Vm[(size_t)(k - 128) * Hc + col];
      else              v =  Um[(size_t)(k - 256) * Hc + col];
      dst[e] = f2bf(v);
    }
  } else if (id < 507904) {                             // gamma weights
    const int id2 = id - 491520;
    const int l = id2 & 63; int u = id2 >> 6;
    const int kb = u & 3; u >>= 2;
    const int tile = u & 1; const int mem = u >> 1;
    const int col = mem * 32 + tile * 16 + (l & 15);
    const int k0 = kb * 32 + (l >> 4) * 8;
    unsigned short* dst = wG + ((((size_t)mem * 2 + tile) * 4 + kb) * 64 + l) * 8;
    #pragma unroll
    for (int e = 0; e < 8; ++e) dst[e] = f2bf(Wgh[(size_t)(k0 + e) * Hc + col]);
  } else if (id < 510976) {                             // bias = b + colsum(V)
    const int id3 = id - 507904;
    const int c16 = id3 & 15; int u = id3 >> 4;
    const int tile = u % 6; const int mem = u / 6;
    const int role = tile >> 1;
    const float* Vm = role == 0 ? Vz : (role == 1 ? Vr : Vh);
    const float* bm = role == 0 ? bz : (role == 1 ? br : bh);
    const int col = mem * 32 + (tile & 1) * 16 + c16;
    float s = bm[col];
    for (int d = 0; d < 128; ++d) s += Vm[(size_t)d * Hc + col];
    bias[mem * 96 + tile * 16 + c16] = s;
  } else if (id < 512000) {
    bg[id - 510976] = bgh[id - 510976];
  }
}

// async-stage one 32x512B chunk (swizzled) into an LDS buffer; 2 issues/wave
__device__ __forceinline__ void issue_chunk(const unsigned short* gsrc, int colbase,
                                            char* achbuf, int w, int lane) {
  #pragma unroll
  for (int j = 0; j < 2; ++j) {
    const int seg  = w * 2 + j;
    const int rrow = seg * 2 + (lane >> 5);
    const unsigned inrow = (unsigned)((lane & 31) * 16);
    const unsigned goff  = inrow ^ (unsigned)((rrow & 7) * 64);
    const unsigned char* gp = (const unsigned char*)(gsrc + (size_t)rrow * Hc + colbase) + goff;
    __builtin_amdgcn_global_load_lds((g_as1_u32*)gp, (l_as3_u32*)(achbuf + seg * 1024),
                                     16, 0, /*sc0|sc1*/ 0x11);
  }
}

template<int S>
__device__ __forceinline__ void mfma_slot(const short* achb, int afr, int swiz,
                                          const short* wlrl, const short8v (&vw)[2][KB_V],
                                          const short* wsrl, float4v& a0, float4v& a1) {
  #pragma unroll
  for (int kk = 0; kk < 8; ++kk) {
    const int kb = S * 8 + kk;
    short8v av = *(const short8v*)(achb + afr + ((kk * 32) ^ swiz));
    short8v b0, b1;
    if (kb < KB_L) {
      b0 = *(const short8v*)(wlrl + (0 * KB_L + kb) * 512);
      b1 = *(const short8v*)(wlrl + (1 * KB_L + kb) * 512);
    } else if (kb < KB_L + KB_V) {
      b0 = vw[0][kb - KB_L]; b1 = vw[1][kb - KB_L];
    } else {
      b0 = *(const short8v*)(wsrl + (0 * KB_S + (kb - KB_L - KB_V)) * 512);
      b1 = *(const short8v*)(wsrl + (1 * KB_S + (kb - KB_L - KB_V)) * 512);
    }
    a0 = MFMA_B16(av, b0, a0);
    a1 = MFMA_B16(av, b1, a1);
  }
}

// pack 2 bf16 (cols c*16+l15, c=0/1) -> row-contig uint32 stores via shfl pairing
__device__ __forceinline__ void store_row32(unsigned short* gbase, int rowq, int mem,
                                            int l15, int q4, unsigned short v0,
                                            unsigned short v1) {
  int s1 = q4 * 16 + ((2 * l15) & 15);
  int a0 = __shfl((int)v0, s1), a1 = __shfl((int)v1, s1);
  unsigned lo = (l15 < 8) ? (unsigned)a0 : (unsigned)a1;
  int s2 = q4 * 16 + ((2 * l15 + 1) & 15);
  int b0 = __shfl((int)v0, s2), b1 = __shfl((int)v1, s2);
  unsigned hi = (l15 < 8) ? (unsigned)b0 : (unsigned)b1;
  unsigned pk = (lo & 0xffffu) | (hi << 16);
  uint32* p = (uint32*)gbase + (size_t)rowq * (Hc / 2) + mem * 16 + l15;
  __hip_atomic_store(p, pk, __ATOMIC_RELAXED, __HIP_MEMORY_SCOPE_AGENT);
}

__device__ __forceinline__ void poll_ge(int* flags, int tval, int l) {
  int sp = 0;
  while (true) {
    int v = (l < 32) ? __hip_atomic_load(&flags[l], __ATOMIC_RELAXED, __HIP_MEMORY_SCOPE_AGENT)
                     : 0x7fffffff;
    if (__all(v >= tval)) break;
    if (++sp > (1 << 16)) break;
    __builtin_amdgcn_s_sleep(1);
  }
}

__global__ __launch_bounds__(512, 2) void k_grud(const unsigned short* __restrict__ xm,
                                                 char* __restrict__ ws) {
  extern __shared__ char smem[];
  short* wLl  = (short*)(smem + LO_WL);
  char*  ach0 = smem + LO_ACH0;
  char*  ach1 = smem + LO_ACH1;
  float* zbuf = (float*)(smem + LO_ZBUF);
  float* gbuf = (float*)(smem + LO_GBUF);
  unsigned short* hbuf = (unsigned short*)(smem + LO_HBUF);
  float* biasl = (float*)(smem + LO_BIAS);
  float* bgl   = (float*)(smem + LO_BG);

  const int bid = blockIdx.x, g = bid & 7, mem = bid >> 3;
  const int tid = threadIdx.x, w = tid >> 6, l = tid & 63;
  const int l15 = l & 15, q4 = l >> 4;
  const int role3 = (w >> 1) < 3 ? (w >> 1) : 2;
  const int mt = w & 1;
  const int row = mt * 16 + l15;          // A-row this lane serves
  const int afr = row * 256 + q4 * 8;     // LDS A-frag base (shorts)
  const int swiz = (row & 7) * 32;        // XOR swizzle (shorts)

  int* fA = (int*)(ws + OFF_FA) + g * 32;
  int* fB = (int*)(ws + OFF_FB) + g * 32;
  unsigned short* hdec = (unsigned short*)(ws + OFF_HDEC) + (size_t)g * 32 * Hc;
  unsigned short* rhb  = (unsigned short*)(ws + OFF_RH)  + (size_t)g * 32 * Hc;
  float* hT = (float*)(ws + OFF_HT);
  const short* wLg = (const short*)(ws + OFF_WL) + (size_t)mem * (6 * KB_L * 512);
  const short* wVg = (const short*)(ws + OFF_WV) + (size_t)mem * (6 * KB_V * 512);
  const short* wSg = (const short*)(ws + OFF_WS) + (size_t)mem * (6 * KB_S * 512);
  const short* wGl = (const short*)(ws + OFF_WG) + (size_t)mem * (2 * 4 * 512) + l * 8;
  const float* biasg = (const float*)(ws + OFF_BIAS) + mem * 96;
  const float* bgg   = (const float*)(ws + OFF_BG) + mem * 32;

  for (int i = tid; i < 6 * KB_L * 512 / 8; i += 512) ((uint4*)wLl)[i] = ((const uint4*)wLg)[i];
  if (tid < 96) biasl[tid] = biasg[tid];
  if (tid < 32) bgl[tid] = bgg[tid];
  for (int i = tid; i < 1056; i += 512) hbuf[i] = 0;

  short8v vw[2][KB_V];
  #pragma unroll
  for (int c = 0; c < 2; ++c)
    #pragma unroll
    for (int i = 0; i < KB_V; ++i)
      vw[c][i] = *(const short8v*)(wVg + (size_t)(((role3 * 2 + c) * KB_V + i) * 512 + l * 8));

  const short* wlrl = wLl + role3 * (2 * KB_L * 512) + l * 8;
  const short* wsrl = wSg + role3 * (2 * KB_S * 512) + l * 8;
  __syncthreads();

  float4v acc0, acc1;
  #pragma unroll 1
  for (int t = 0; t < 256; ++t) {
    const unsigned short* xmt = xm + ((size_t)t * Bc + g * 32) * 256;
    // ---- slot0: K = [x'(128)|m(128)], A direct from global (L2-hot)
    if (w < 6) {
      acc0 = float4v{0.f, 0.f, 0.f, 0.f};
      acc1 = float4v{0.f, 0.f, 0.f, 0.f};
      const unsigned short* xr = xmt + (size_t)row * 256 + q4 * 8;
      #pragma unroll
      for (int kk = 0; kk < 8; ++kk) {
        short8v av = *(const short8v*)(xr + kk * 32);
        short8v b0 = *(const short8v*)(wlrl + (0 * KB_L + kk) * 512);
        short8v b1 = *(const short8v*)(wlrl + (1 * KB_L + kk) * 512);
        acc0 = MFMA_B16(av, b0, acc0);
        acc1 = MFMA_B16(av, b1, acc1);
      }
    } else if (t < 255) {   // gamma(t+1) from m(t+1), weights via L1/L2
      float4v ga0{0.f, 0.f, 0.f, 0.f}, ga1{0.f, 0.f, 0.f, 0.f};
      const unsigned short* mr = xmt + (size_t)Bc * 256 + (size_t)row * 256 + 128 + q4 * 8;
      #pragma unroll
      for (int kb = 0; kb < 4; ++kb) {
        short8v av = *(const short8v*)(mr + kb * 32);
        short8v b0 = *(const short8v*)(wGl + (0 * 4 + kb) * 512);
        short8v b1 = *(const short8v*)(wGl + (1 * 4 + kb) * 512);
        ga0 = MFMA_B16(av, b0, ga0);
        ga1 = MFMA_B16(av, b1, ga1);
      }
      #pragma unroll
      for (int q = 0; q < 4; ++q) {
        const int rq = mt * 16 + q4 * 4 + q;
        gbuf[l15 * 33 + rq]        = __expf(-fmaxf(0.f, ga0[q] + bgl[l15]));
        gbuf[(16 + l15) * 33 + rq] = __expf(-fmaxf(0.f, ga1[q] + bgl[16 + l15]));
      }
    }
    if (w == 7) poll_ge(fB, t, l);
    BARX();
    // ---- phase A: K = h_dec, 4 swizzled chunks, 2-deep async pipeline
    issue_chunk(hdec, 0,   ach0, w, l);
    issue_chunk(hdec, 256, ach1, w, l);
    WAITV2(); BARX();
    if (w < 4) mfma_slot<1>((short*)ach0, afr, swiz, wlrl, vw, wsrl, acc0, acc1);
    BARX();
    issue_chunk(hdec, 512, ach0, w, l);
    WAITV2(); BARX();
    if (w < 4) mfma_slot<2>((short*)ach1, afr, swiz, wlrl, vw, wsrl, acc0, acc1);
    BARX();
    issue_chunk(hdec, 768, ach1, w, l);
    WAITV2(); BARX();
    if (w < 4) mfma_slot<3>((short*)ach0, afr, swiz, wlrl, vw, wsrl, acc0, acc1);
    BARX();
    WAITV0(); BARX();
    if (w < 4) mfma_slot<4>((short*)ach1, afr, swiz, wlrl, vw, wsrl, acc0, acc1);
    // ---- phase A epilogue
    if (w < 2) {            // z -> zbuf
      #pragma unroll
      for (int c = 0; c < 2; ++c) {
        float4v a = c ? acc1 : acc0;
        #pragma unroll
        for (int q = 0; q < 4; ++q) {
          const int rq = mt * 16 + q4 * 4 + q;
          zbuf[(c * 16 + l15) * 33 + rq] = 1.f / (1.f + __expf(-(a[q] + biasl[c * 16 + l15])));
        }
      }
    } else if (w < 4) {     // r -> rh broadcast (LLC)
      #pragma unroll
      for (int q = 0; q < 4; ++q) {
        const int rq = mt * 16 + q4 * 4 + q;
        unsigned short u0, u1;
        #pragma unroll
        for (int c = 0; c < 2; ++c) {
          float4v a = c ? acc1 : acc0;
          const float rv = 1.f / (1.f + __expf(-(a[q] + biasl[32 + c * 16 + l15])));
          const float hd = bf2f(hbuf[(c * 16 + l15) * 33 + rq]);
          unsigned short pv = f2bf(rv * hd);
          if (c == 0) u0 = pv; else u1 = pv;
        }
        store_row32(rhb, rq, mem, l15, q4, u0, u1);
      }
      WAITV0();
    }
    BARX();
    if (tid == 0) __hip_atomic_store(&fA[mem], t + 1, __ATOMIC_RELAXED, __HIP_MEMORY_SCOPE_AGENT);
    if (w == 7) poll_ge(fA, t + 1, l);
    BARX();
    // ---- phase B: K = r*h_dec, 4 chunks
    issue_chunk(rhb, 0,   ach0, w, l);
    issue_chunk(rhb, 256, ach1, w, l);
    WAITV2(); BARX();
    if (w == 4 || w == 5) mfma_slot<1>((short*)ach0, afr, swiz, wlrl, vw, wsrl, acc0, acc1);
    BARX();
    issue_chunk(rhb, 512, ach0, w, l);
    WAITV2(); BARX();
    if (w == 4 || w == 5) mfma_slot<2>((short*)ach1, afr, swiz, wlrl, vw, wsrl, acc0, acc1);
    BARX();
    issue_chunk(rhb, 768, ach1, w, l);
    WAITV2(); BARX();
    if (w == 4 || w == 5) mfma_slot<3>((short*)ach0, afr, swiz, wlrl, vw, wsrl, acc0, acc1);
    BARX();
    WAITV0(); BARX();
    if (w == 4 || w == 5) mfma_slot<4>((short*)ach1, afr, swiz, wlrl, vw, wsrl, acc0, acc1);
    // ---- phase B epilogue: h~, h_new, h_dec(t+1)
    if (w == 4 || w == 5) {
      #pragma unroll
      for (int q = 0; q < 4; ++q) {
        const int rq = mt * 16 + q4 * 4 + q;
        unsigned short u0 = 0, u1 = 0;
        #pragma unroll
        for (int c = 0; c < 2; ++c) {
          float4v a = c ? acc1 : acc0;
          const int cc = c * 16 + l15;
          const float e = __expf(2.f * (a[q] + biasl[64 + cc]));
          const float ht = 1.f - 2.f / (e + 1.f);
          const float zv = zbuf[cc * 33 + rq];
          const float hd = bf2f(hbuf[cc * 33 + rq]);
          const float hn = (1.f - zv) * hd + zv * ht;
          if (t < 255) {
            unsigned short pv = f2bf(gbuf[cc * 33 + rq] * hn);
            hbuf[cc * 33 + rq] = pv;
            if (c == 0) u0 = pv; else u1 = pv;
          } else {
            hT[(size_t)(g * 32 + rq) * Hc + (mem * 32 + cc)] = hn;
          }
        }
        if (t < 255) store_row32(hdec, rq, mem, l15, q4, u0, u1);
      }
      WAITV0();
    }
    BARX();
    if (tid == 0) __hip_atomic_store(&fB[mem], t + 1, __ATOMIC_RELAXED, __HIP_MEMORY_SCOPE_AGENT);
  }
}

// out = h_T @ dec_W + dec_b
__global__ void k_dec(const char* __restrict__ ws, const float* __restrict__ decW,
                      const float* __restrict__ decb, float* __restrict__ out) {
  const float* hT = (const float*)(ws + OFF_HT);
  __shared__ float red[4][64];
  const int b = blockIdx.x, tid = threadIdx.x;
  const int col = tid & 63, part = tid >> 6;
  float acc = 0.f;
  const float* hrow = hT + (size_t)b * Hc + part * 256;
  for (int i = 0; i < 256; ++i) acc += hrow[i] * decW[(size_t)(part * 256 + i) * 64 + col];
  red[part][col] = acc;
  __syncthreads();
  if (part == 0) out[b * 64 + col] = red[0][col] + red[1][col] + red[2][col] + red[3][col] + decb[col];
}

extern "C" void kernel_launch(void* const* d_in, const int* in_sizes, int n_in,
                              void* d_out, int out_size, void* d_ws, size_t ws_size,
                              hipStream_t stream) {
  const float* x    = (const float*)d_in[0];
  const float* delt = (const float*)d_in[1];
  const float* m    = (const float*)d_in[2];
  const float* W_r = (const float*)d_in[3],  *U_r = (const float*)d_in[4];
  const float* V_r = (const float*)d_in[5],  *b_r = (const float*)d_in[6];
  const float* W_z = (const float*)d_in[7],  *U_z = (const float*)d_in[8];
  const float* V_z = (const float*)d_in[9],  *b_z = (const float*)d_in[10];
  const float* W_h = (const float*)d_in[11], *U_h = (const float*)d_in[12];
  const float* V_h = (const float*)d_in[13], *b_h = (const float*)d_in[14];
  const float* Wgx = (const float*)d_in[15], *bgx = (const float*)d_in[16];
  const float* Wgh = (const float*)d_in[17], *bgh = (const float*)d_in[18];
  const float* dW  = (const float*)d_in[19], *db  = (const float*)d_in[20];
  char* ws = (char*)d_ws;
  float* out = (float*)d_out;

  (void)hipFuncSetAttribute((const void*)k_grud,
                            hipFuncAttributeMaxDynamicSharedMemorySize, SMEM_BYTES);

  k_init<<<516, 256, 0, stream>>>(ws);
  k_xm<<<32768, 256, 0, stream>>>(x, delt, m, Wgx, bgx, (unsigned short*)(ws + OFF_XM));
  k_pack<<<2000, 256, 0, stream>>>(W_z, U_z, V_z, b_z, W_r, U_r, V_r, b_r,
                                   W_h, U_h, V_h, b_h, Wgh, bgh, ws);
  k_grud<<<256, 512, SMEM_BYTES, stream>>>((const unsigned short*)(ws + OFF_XM), ws);
  k_dec<<<256, 256, 0, stream>>>(ws, dW, db, out);
}